// Round 5
// baseline (2010.857 us; speedup 1.0000x reference)
//
#include <hip/hip_runtime.h>
#include <cstddef>
#include <cstdint>

// K-means (Lloyd, 10 fixed iters): N=1024 pts, K=64 centroids, D=98304.
// d_in[0]=x f32[1024*98304], d_in[1]=centroid f32[64*98304]
// d_out = concat(final state [64*98304] f32, last choice [1024] as f32)
//
// Round 5: (a) dot kernel: A-operand streamed direct global->reg (16 rows x
// 64B fully coalesced per instr), register double-buffered; only B (centroids)
// staged in LDS (18.4KB) -> less LDS traffic, fewer insts; (b) plane convert +
// c2 partials fused into gather/update (per-iter convert kernel gone).

#define N_PTS  1024
#define K_C    64
#define D_DIM  98304
#define ITERS  10
#define SPLITD 64          // D-split for dot kernel (partial = 16 MB)
#define BM     64          // X rows per block tile
#define DC     64          // d-chunk per step
#define LDSP   72          // padded LDS row stride (bf16): 144B stride -> 2-way max (free)
#define NCHK   96          // D/1024 chunks for gather/update + c2 partials
#define CCHK   12          // D/8192 chunks for convert kernel

typedef __attribute__((ext_vector_type(8))) short bf16x8;
typedef __attribute__((ext_vector_type(8))) unsigned short ushort8;
typedef __attribute__((ext_vector_type(4))) float f32x4;

__device__ __forceinline__ unsigned short f2bf(float x) {   // RNE f32->bf16
    unsigned u = __float_as_uint(x);
    u = (u + 0x7FFFu + ((u >> 16) & 1u)) >> 16;
    return (unsigned short)u;
}
__device__ __forceinline__ float bf2f(unsigned short b) {
    return __uint_as_float((unsigned)b << 16);
}
__device__ __forceinline__ void cvt2(float x, unsigned short& h, unsigned short& l) {
    h = f2bf(x);
    l = f2bf(x - bf2f(h));
}

__device__ __forceinline__ float block_sum256(float s) {
    #pragma unroll
    for (int o = 32; o; o >>= 1) s += __shfl_down(s, o);
    __shared__ float red[4];
    int lane = threadIdx.x & 63, w = threadIdx.x >> 6;
    if (lane == 0) red[w] = s;
    __syncthreads();
    return red[0] + red[1] + red[2] + red[3];
}

// ---------------- convert rows fp32 -> bf16 hi/lo planes + sumsq partials ----------------
__global__ __launch_bounds__(256) void convert_kernel(const float* __restrict__ A,
                                                      unsigned short* __restrict__ Ph,
                                                      unsigned short* __restrict__ Pl,
                                                      float* __restrict__ sq_part) {
    const int n = blockIdx.x, j = blockIdx.y;
    const size_t base = (size_t)n * D_DIM + (size_t)j * 8192;
    const int t = threadIdx.x;
    float ss = 0.f;
    #pragma unroll
    for (int i = 0; i < 4; ++i) {
        size_t e = base + (size_t)i * 2048 + t * 8;
        float4 a = *reinterpret_cast<const float4*>(A + e);
        float4 b = *reinterpret_cast<const float4*>(A + e + 4);
        ss += a.x*a.x + a.y*a.y + a.z*a.z + a.w*a.w;
        ss += b.x*b.x + b.y*b.y + b.z*b.z + b.w*b.w;
        ushort4 h0, l0, h1, l1;
        cvt2(a.x, h0.x, l0.x); cvt2(a.y, h0.y, l0.y);
        cvt2(a.z, h0.z, l0.z); cvt2(a.w, h0.w, l0.w);
        cvt2(b.x, h1.x, l1.x); cvt2(b.y, h1.y, l1.y);
        cvt2(b.z, h1.z, l1.z); cvt2(b.w, h1.w, l1.w);
        *reinterpret_cast<ushort4*>(Ph + e)     = h0;
        *reinterpret_cast<ushort4*>(Ph + e + 4) = h1;
        *reinterpret_cast<ushort4*>(Pl + e)     = l0;
        *reinterpret_cast<ushort4*>(Pl + e + 4) = l1;
    }
    ss = block_sum256(ss);
    if (t == 0) sq_part[n * CCHK + j] = ss;
}

__global__ __launch_bounds__(256) void reduce_sq_kernel(const float* __restrict__ sq_part,
                                                        float* __restrict__ out, int rows) {
    int n = blockIdx.x * 256 + threadIdx.x;
    if (n >= rows) return;
    float s = 0.f;
    #pragma unroll
    for (int j = 0; j < CCHK; ++j) s += sq_part[n * CCHK + j];
    out[n] = s;
}

// ---------------- dot[n][k] partial: bf16 hi/lo x3 MFMA, A direct-global ----------------
// grid (SPLITD, N/BM): same-seg blocks land on same XCD (64%8==0) -> S in L2.
__global__ __launch_bounds__(256, 5) void mfma_dot_kernel(const unsigned short* __restrict__ Xh,
                                                          const unsigned short* __restrict__ Xl,
                                                          const unsigned short* __restrict__ Sh,
                                                          const unsigned short* __restrict__ Sl,
                                                          float* __restrict__ partial) {
    __shared__ alignas(16) short Bh[K_C][LDSP];
    __shared__ alignas(16) short Bl[K_C][LDSP];

    const int seg = blockIdx.x, nblk = blockIdx.y;
    const int t = threadIdx.x;
    const int wid = t >> 6, lane = t & 63;
    const int d_begin = seg * (D_DIM / SPLITD);
    const int NCH = (D_DIM / SPLITD) / DC;          // 24 (even)

    // A: lane-fixed row, direct from global (16 rows x 64B coalesced per instr)
    const int arow = nblk * BM + wid * 16 + (lane & 15);
    const int ko = (lane >> 4) * 8;                 // 0,8,16,24
    const unsigned short* xh = Xh + (size_t)arow * D_DIM;
    const unsigned short* xl = Xl + (size_t)arow * D_DIM;

    // B staging: thread t covers row t>>2, cols (t&3)*16 .. +16 (32B/plane)
    const int sr = t >> 2, sc = (t & 3) * 16;
    const unsigned short* shp = Sh + (size_t)sr * D_DIM;
    const unsigned short* slp = Sl + (size_t)sr * D_DIM;

    ushort8 s0, s1, s2, s3;            // staged B (hi:sc, hi:sc+8, lo:sc, lo:sc+8)
    bf16x8 aEh0, aEh1, aEl0, aEl1;     // A frags, even-chunk buffer (ks=0,1)
    bf16x8 aOh0, aOh1, aOl0, aOl1;     // odd-chunk buffer

    auto loadB = [&](int d0) {
        s0 = *reinterpret_cast<const ushort8*>(shp + d0 + sc);
        s1 = *reinterpret_cast<const ushort8*>(shp + d0 + sc + 8);
        s2 = *reinterpret_cast<const ushort8*>(slp + d0 + sc);
        s3 = *reinterpret_cast<const ushort8*>(slp + d0 + sc + 8);
    };
    auto storeB = [&]() {
        *reinterpret_cast<ushort8*>(&Bh[sr][sc])     = s0;
        *reinterpret_cast<ushort8*>(&Bh[sr][sc + 8]) = s1;
        *reinterpret_cast<ushort8*>(&Bl[sr][sc])     = s2;
        *reinterpret_cast<ushort8*>(&Bl[sr][sc + 8]) = s3;
    };

    f32x4 acc[4];
    #pragma unroll
    for (int i = 0; i < 4; ++i) acc[i] = f32x4{0.f, 0.f, 0.f, 0.f};

    #define LOADA(bh0, bh1, bl0, bl1, d0)                                        \
        bh0 = *reinterpret_cast<const bf16x8*>(xh + (d0) + ko);                  \
        bh1 = *reinterpret_cast<const bf16x8*>(xh + (d0) + 32 + ko);             \
        bl0 = *reinterpret_cast<const bf16x8*>(xl + (d0) + ko);                  \
        bl1 = *reinterpret_cast<const bf16x8*>(xl + (d0) + 32 + ko);

    #define MFMAS(ah0, ah1, al0, al1)                                            \
        _Pragma("unroll")                                                        \
        for (int nb = 0; nb < 4; ++nb) {                                         \
            const int br = nb * 16 + (lane & 15);                                \
            bf16x8 bh = *reinterpret_cast<const bf16x8*>(&Bh[br][ko]);           \
            bf16x8 bl = *reinterpret_cast<const bf16x8*>(&Bl[br][ko]);           \
            acc[nb] = __builtin_amdgcn_mfma_f32_16x16x32_bf16(ah0, bh, acc[nb], 0, 0, 0); \
            acc[nb] = __builtin_amdgcn_mfma_f32_16x16x32_bf16(ah0, bl, acc[nb], 0, 0, 0); \
            acc[nb] = __builtin_amdgcn_mfma_f32_16x16x32_bf16(al0, bh, acc[nb], 0, 0, 0); \
        }                                                                        \
        _Pragma("unroll")                                                        \
        for (int nb = 0; nb < 4; ++nb) {                                         \
            const int br = nb * 16 + (lane & 15);                                \
            bf16x8 bh = *reinterpret_cast<const bf16x8*>(&Bh[br][32 + ko]);      \
            bf16x8 bl = *reinterpret_cast<const bf16x8*>(&Bl[br][32 + ko]);      \
            acc[nb] = __builtin_amdgcn_mfma_f32_16x16x32_bf16(ah1, bh, acc[nb], 0, 0, 0); \
            acc[nb] = __builtin_amdgcn_mfma_f32_16x16x32_bf16(ah1, bl, acc[nb], 0, 0, 0); \
            acc[nb] = __builtin_amdgcn_mfma_f32_16x16x32_bf16(al1, bh, acc[nb], 0, 0, 0); \
        }

    loadB(d_begin);
    LOADA(aEh0, aEh1, aEl0, aEl1, d_begin);
    for (int c = 0; c < NCH; c += 2) {
        // even chunk: compute E, prefetch O
        __syncthreads();
        storeB();
        __syncthreads();
        {
            int dn = d_begin + (c + 1) * DC;
            loadB(dn);
            LOADA(aOh0, aOh1, aOl0, aOl1, dn);
        }
        MFMAS(aEh0, aEh1, aEl0, aEl1);
        // odd chunk: compute O, prefetch E
        __syncthreads();
        storeB();
        __syncthreads();
        if (c + 2 < NCH) {
            int dn = d_begin + (c + 2) * DC;
            loadB(dn);
            LOADA(aEh0, aEh1, aEl0, aEl1, dn);
        }
        MFMAS(aOh0, aOh1, aOl0, aOl1);
    }
    #undef LOADA
    #undef MFMAS

    // C/D layout (verified): col = lane&15, row = (lane>>4)*4 + reg
    #pragma unroll
    for (int nb = 0; nb < 4; ++nb)
        #pragma unroll
        for (int r = 0; r < 4; ++r) {
            int row = wid * 16 + (lane >> 4) * 4 + r;
            int col = nb * 16 + (lane & 15);
            int n = nblk * BM + row;
            partial[((size_t)seg * N_PTS + n) * K_C + col] = acc[nb][r];
        }
}

// ---------------- reduce split-D partials (init path only) ----------------
__global__ __launch_bounds__(256) void reduce_dot_kernel(const float* __restrict__ partial,
                                                         float* __restrict__ dot) {
    int i = blockIdx.x * 256 + threadIdx.x;
    float s = 0.f;
    #pragma unroll 8
    for (int p = 0; p < SPLITD; ++p) s += partial[(size_t)p * N_PTS * K_C + i];
    dot[i] = s;
}

// ---------------- init: per-centroid argmin over points ----------------
__global__ __launch_bounds__(256) void argmin_n_kernel(const float* __restrict__ dot,
                                                       const float* __restrict__ x2,
                                                       int* __restrict__ choice_pts) {
    int k = blockIdx.x;
    float best = 3.4e38f; int bi = N_PTS;
    for (int n = threadIdx.x; n < N_PTS; n += 256) {
        float v = fmaf(-2.f, dot[n * K_C + k], x2[n]);
        if (v < best || (v == best && n < bi)) { best = v; bi = n; }
    }
    #pragma unroll
    for (int off = 32; off; off >>= 1) {
        float v2 = __shfl_down(best, off);
        int   i2 = __shfl_down(bi, off);
        if (v2 < best || (v2 == best && i2 < bi)) { best = v2; bi = i2; }
    }
    __shared__ float bv[4]; __shared__ int bix[4];
    int lane = threadIdx.x & 63, wid = threadIdx.x >> 6;
    if (lane == 0) { bv[wid] = best; bix[wid] = bi; }
    __syncthreads();
    if (threadIdx.x == 0) {
        for (int w = 1; w < 4; ++w)
            if (bv[w] < best || (bv[w] == best && bix[w] < bi)) { best = bv[w]; bi = bix[w]; }
        choice_pts[k] = bi;
    }
}

// ---------------- gather snapped centroids + planes + c2 partials ----------------
__global__ __launch_bounds__(256) void gather_kernel(const float* __restrict__ X,
                                                     const int* __restrict__ choice_pts,
                                                     float* __restrict__ state,
                                                     unsigned short* __restrict__ Sh,
                                                     unsigned short* __restrict__ Sl,
                                                     float* __restrict__ c2p) {
    int k = blockIdx.x;
    int c = choice_pts[k];
    size_t d = (size_t)blockIdx.y * 1024 + threadIdx.x * 4;
    size_t o = (size_t)k * D_DIM + d;
    float4 v = *reinterpret_cast<const float4*>(X + (size_t)c * D_DIM + d);
    *reinterpret_cast<float4*>(state + o) = v;
    ushort4 h, l;
    cvt2(v.x, h.x, l.x); cvt2(v.y, h.y, l.y); cvt2(v.z, h.z, l.z); cvt2(v.w, h.w, l.w);
    *reinterpret_cast<ushort4*>(Sh + o) = h;
    *reinterpret_cast<ushort4*>(Sl + o) = l;
    float ss = block_sum256(v.x*v.x + v.y*v.y + v.z*v.z + v.w*v.w);
    if (threadIdx.x == 0) c2p[k * NCHK + blockIdx.y] = ss;
}

// ---------------- assign: fused split-D reduce + argmin over K=64 ----------------
__global__ __launch_bounds__(256) void assign_kernel(const float* __restrict__ partial,
                                                     const float* __restrict__ c2p,
                                                     int* __restrict__ choice) {
    int wid = threadIdx.x >> 6, lane = threadIdx.x & 63;
    int n = blockIdx.x * 4 + wid;
    float s = 0.f;
    #pragma unroll 8
    for (int p = 0; p < SPLITD; ++p) s += partial[((size_t)p * N_PTS + n) * K_C + lane];
    float c2 = 0.f;
    const float* cp2 = c2p + lane * NCHK;
    #pragma unroll 8
    for (int j = 0; j < NCHK; ++j) c2 += cp2[j];
    float v = fmaf(-2.f, s, c2);
    int bi = lane;
    #pragma unroll
    for (int m = 32; m; m >>= 1) {
        float v2 = __shfl_xor(v, m);
        int   i2 = __shfl_xor(bi, m);
        if (v2 < v || (v2 == v && i2 < bi)) { v = v2; bi = i2; }
    }
    if (lane == 0) choice[n] = bi;
}

// ---------------- init prev-assignment state ----------------
__global__ __launch_bounds__(256) void init_prev_kernel(int* __restrict__ chp,
                                                        int* __restrict__ ctp) {
    int t = blockIdx.x * 256 + threadIdx.x;
    if (t < N_PTS) chp[t] = -1;
    if (t < K_C)   ctp[t] = 0;
}

// ---------------- sorted change lists (1 block, 1024 thr, deterministic) ----------------
__global__ __launch_bounds__(1024) void changes_kernel(const int* __restrict__ ch_new,
                                                       const int* __restrict__ ch_prev,
                                                       int* __restrict__ add_n,
                                                       int* __restrict__ astart,
                                                       int* __restrict__ sub_n,
                                                       int* __restrict__ sstart,
                                                       int* __restrict__ counts_new) {
    __shared__ int chn[N_PTS];
    __shared__ int chp[N_PTS];
    __shared__ int acnt[K_C], scnt[K_C], hcnt[K_C];
    __shared__ int ast[K_C + 1], sst[K_C + 1];
    const int t = threadIdx.x;
    if (t < K_C) { acnt[t] = 0; scnt[t] = 0; hcnt[t] = 0; }
    __syncthreads();
    const int cn = ch_new[t], cp = ch_prev[t];
    chn[t] = cn; chp[t] = cp;
    atomicAdd(&hcnt[cn], 1);
    const bool changed = (cn != cp);
    if (changed) {
        atomicAdd(&acnt[cn], 1);
        if (cp >= 0) atomicAdd(&scnt[cp], 1);
    }
    __syncthreads();
    if (t == 0) {
        int a = 0;
        for (int k = 0; k < K_C; ++k) { ast[k] = a; a += acnt[k]; }
        ast[K_C] = a;
    }
    if (t == 64) {
        int a = 0;
        for (int k = 0; k < K_C; ++k) { sst[k] = a; a += scnt[k]; }
        sst[K_C] = a;
    }
    __syncthreads();
    int ra = 0, rs = 0;
    for (int m = 0; m < t; ++m) {
        int cm = chn[m], pm = chp[m];
        bool ch = (cm != pm);
        ra += (ch && cm == cn);
        rs += (ch && pm == cp);
    }
    if (changed) {
        add_n[ast[cn] + ra] = t;
        if (cp >= 0) sub_n[sst[cp] + rs] = t;
    }
    if (t <= K_C) { astart[t] = ast[t]; sstart[t] = sst[t]; }
    if (t < K_C) counts_new[t] = hcnt[t];
}

// ---------------- incremental update + fused plane convert + c2 partials ----------------
// sum = state*cp + adds - subs (ascending-n, deterministic). Untouched or
// emptied clusters: keep state AND planes AND c2p (stale == consistent).
__global__ __launch_bounds__(256) void update_kernel(const float* __restrict__ X,
                                                     const int* __restrict__ add_n,
                                                     const int* __restrict__ astart,
                                                     const int* __restrict__ sub_n,
                                                     const int* __restrict__ sstart,
                                                     const int* __restrict__ counts_new,
                                                     const int* __restrict__ counts_prev,
                                                     float* __restrict__ state,
                                                     unsigned short* __restrict__ Sh,
                                                     unsigned short* __restrict__ Sl,
                                                     float* __restrict__ c2p) {
    const int k = blockIdx.x;
    const int ab = astart[k], ae = astart[k + 1];
    const int sb = sstart[k], se = sstart[k + 1];
    if (ab == ae && sb == se) return;            // untouched
    const int cn = counts_new[k], cp = counts_prev[k];
    const size_t d = (size_t)blockIdx.y * 1024 + threadIdx.x * 4;
    const size_t o = (size_t)k * D_DIM + d;

    float sx = 0.f, sy = 0.f, sz = 0.f, sw = 0.f;
    if (cp > 0) {
        float4 st = *reinterpret_cast<const float4*>(state + o);
        float c = (float)cp;
        sx = st.x * c; sy = st.y * c; sz = st.z * c; sw = st.w * c;
    }
    for (int i = ab; i < ae; ++i) {
        const float4 v = *reinterpret_cast<const float4*>(X + (size_t)add_n[i] * D_DIM + d);
        sx += v.x; sy += v.y; sz += v.z; sw += v.w;
    }
    for (int i = sb; i < se; ++i) {
        const float4 v = *reinterpret_cast<const float4*>(X + (size_t)sub_n[i] * D_DIM + d);
        sx -= v.x; sy -= v.y; sz -= v.z; sw -= v.w;
    }
    if (cn > 0) {
        float inv = 1.f / (float)cn;
        float4 m; m.x = sx * inv; m.y = sy * inv; m.z = sz * inv; m.w = sw * inv;
        *reinterpret_cast<float4*>(state + o) = m;
        ushort4 h, l;
        cvt2(m.x, h.x, l.x); cvt2(m.y, h.y, l.y); cvt2(m.z, h.z, l.z); cvt2(m.w, h.w, l.w);
        *reinterpret_cast<ushort4*>(Sh + o) = h;
        *reinterpret_cast<ushort4*>(Sl + o) = l;
        float ss = block_sum256(m.x*m.x + m.y*m.y + m.z*m.z + m.w*m.w);
        if (threadIdx.x == 0) c2p[k * NCHK + blockIdx.y] = ss;
    }
}

// ---------------- write last-iteration assignments as float ----------------
__global__ __launch_bounds__(256) void choice_out_kernel(const int* __restrict__ choice,
                                                         float* __restrict__ out) {
    int n = blockIdx.x * 256 + threadIdx.x;
    if (n < N_PTS) out[n] = (float)choice[n];
}

extern "C" void kernel_launch(void* const* d_in, const int* in_sizes, int n_in,
                              void* d_out, int out_size, void* d_ws, size_t ws_size,
                              hipStream_t stream) {
    const float* X  = (const float*)d_in[0];
    const float* C0 = (const float*)d_in[1];
    float* state      = (float*)d_out;
    float* out_choice = state + (size_t)K_C * D_DIM;

    char* w = (char*)d_ws;
    size_t off = 0;
    auto alloc = [&](size_t bytes) { void* p = w + off; off = (off + bytes + 255) & ~(size_t)255; return p; };
    unsigned short* Xh = (unsigned short*)alloc((size_t)N_PTS * D_DIM * 2);
    unsigned short* Xl = (unsigned short*)alloc((size_t)N_PTS * D_DIM * 2);
    unsigned short* Sh = (unsigned short*)alloc((size_t)K_C * D_DIM * 2);
    unsigned short* Sl = (unsigned short*)alloc((size_t)K_C * D_DIM * 2);
    float* partial = (float*)alloc((size_t)SPLITD * N_PTS * K_C * 4);   // 16 MB
    float* dotb    = (float*)alloc((size_t)N_PTS * K_C * 4);
    float* x2p     = (float*)alloc((size_t)N_PTS * CCHK * 4);
    float* x2      = (float*)alloc((size_t)N_PTS * 4);
    float* c0sq    = (float*)alloc((size_t)K_C * CCHK * 4);
    float* c2p     = (float*)alloc((size_t)K_C * NCHK * 4);
    int* cpts      = (int*)alloc(256);
    int* ch[2];
    ch[0] = (int*)alloc((size_t)N_PTS * 4);
    ch[1] = (int*)alloc((size_t)N_PTS * 4);
    int* ct[2];
    ct[0] = (int*)alloc(256);
    ct[1] = (int*)alloc(256);
    int* add_n  = (int*)alloc((size_t)N_PTS * 4);
    int* astart = (int*)alloc(512);
    int* sub_n  = (int*)alloc((size_t)N_PTS * 4);
    int* sstart = (int*)alloc(512);

    dim3 b256(256);

    // one-time: X -> bf16 hi/lo planes + x2
    convert_kernel<<<dim3(N_PTS, CCHK), b256, 0, stream>>>(X, Xh, Xl, x2p);
    reduce_sq_kernel<<<dim3(4), b256, 0, stream>>>(x2p, x2, N_PTS);

    // ---- init ('resuming'): snap each centroid to its nearest sample ----
    convert_kernel<<<dim3(K_C, CCHK), b256, 0, stream>>>(C0, Sh, Sl, c0sq);
    mfma_dot_kernel<<<dim3(SPLITD, N_PTS / BM), b256, 0, stream>>>(Xh, Xl, Sh, Sl, partial);
    reduce_dot_kernel<<<dim3(N_PTS * K_C / 256), b256, 0, stream>>>(partial, dotb);
    argmin_n_kernel<<<K_C, b256, 0, stream>>>(dotb, x2, cpts);
    gather_kernel<<<dim3(K_C, NCHK), b256, 0, stream>>>(X, cpts, state, Sh, Sl, c2p);
    init_prev_kernel<<<dim3(4), b256, 0, stream>>>(ch[0], ct[0]);

    // ---- 10 Lloyd iterations ----
    for (int it = 0; it < ITERS; ++it) {
        int prev = it & 1, cur = 1 - prev;
        mfma_dot_kernel<<<dim3(SPLITD, N_PTS / BM), b256, 0, stream>>>(Xh, Xl, Sh, Sl, partial);
        assign_kernel<<<dim3(N_PTS / 4), b256, 0, stream>>>(partial, c2p, ch[cur]);
        changes_kernel<<<1, dim3(1024), 0, stream>>>(ch[cur], ch[prev], add_n, astart,
                                                     sub_n, sstart, ct[cur]);
        update_kernel<<<dim3(K_C, NCHK), b256, 0, stream>>>(X, add_n, astart, sub_n, sstart,
                                                            ct[cur], ct[prev], state, Sh, Sl, c2p);
    }

    choice_out_kernel<<<dim3(N_PTS / 256), b256, 0, stream>>>(ch[0], out_choice);
}